// Round 6
// baseline (299.415 us; speedup 1.0000x reference)
//
#include <hip/hip_runtime.h>

// VQ-VAE vector quantizer, MI355X — v5: 1 token/thread (z truly in VGPRs),
// K-split x4 with XCD-local mapping, (token x d-quarter) epilogue.
// Inputs:  d_in[0] = z_e  f32 (32,64,64,64)  [B,D,H,W]
//          d_in[1] = emb  f32 (512,64)       [K,D]
// Output (flat f32): [0..8388608) z_q_st | [8388608..8388613) scalars
//                    (loss_vq, perplexity, codes_used, usage_ratio, avg_dist2)
//                    | [8388613..+131072) indices as float
// ws: [0..16) f64 sums | [16..2064) int counts[512] | [2064..4112) f32 see[512]
//     | [4608..4608+4MiB) float2 pairs[4][131072] {best, idx-bits}

#define NTOK 131072
#define DDIM 64
#define KCB  512
#define KQ   128      // codes per k-slice
#define NSPLIT 4
#define HWSZ 4096

__global__ void vq_see_kernel(const float* __restrict__ emb,
                              float* __restrict__ see) {
  int k = blockIdx.x * 64 + threadIdx.x;
  if (k < KCB) {
    const float* e = emb + k * DDIM;
    float s = 0.f;
#pragma unroll
    for (int d = 0; d < DDIM; ++d) s = fmaf(e[d], e[d], s);
    see[k] = s;
  }
}

// Search: 2048 blocks x 256 thr. 1 token/thread, 128-code slice in LDS.
// XCD-local decode: blocks {x, x+8, x+16, x+24} share tb and cover kq=0..3;
// they land on the same XCD (dispatch round-robins blockIdx%8) -> each
// token's z_e is HBM-fetched once per XCD, L2 serves the other 3 slices.
__global__ __launch_bounds__(256, 4) void vq_search_kernel(
    const float* __restrict__ z_e, const float* __restrict__ emb,
    const float* __restrict__ see, float2* __restrict__ pairs) {
  __shared__ float4 ldsE[KQ][16];
  __shared__ float  ldsS[KQ];

  const int tid = threadIdx.x;
  const int x   = blockIdx.x;
  const int tb  = (x & 7) | ((x >> 5) << 3);   // 0..511 token groups of 256
  const int kq  = (x >> 3) & 3;                // 0..3 k-slice
  const int kqbase = kq * KQ;

  // stage the 32KB code slice + see slice into LDS (coalesced)
  {
    const float4* src = reinterpret_cast<const float4*>(emb) + kqbase * 16;
    float4* dst = &ldsE[0][0];
#pragma unroll
    for (int v = tid; v < KQ * 16; v += 256) dst[v] = src[v];
    if (tid < KQ) ldsS[tid] = see[kqbase + tid];
  }
  __syncthreads();

  // one token per thread, lanes contiguous in hw -> coalesced loads
  const int tok = tb * 256 + tid;
  const int b   = tok >> 12;
  const int hw  = tok & 4095;
  const float* zp = z_e + (size_t)b * DDIM * HWSZ + hw;

  float z[DDIM];
#pragma unroll
  for (int d = 0; d < DDIM; ++d) z[d] = zp[(size_t)d * HWSZ];

  // ||z||^2 sequential fp32 (reference rounding)
  float szz = 0.f;
#pragma unroll
  for (int d = 0; d < DDIM; ++d) szz = fmaf(z[d], z[d], szz);

  // discourage rematerialization of the z loads
#pragma unroll
  for (int d = 0; d < DDIM; ++d) asm volatile("" : "+v"(z[d]));

  float best = 3.4e38f;
  int   bidx = kqbase;

  for (int kk = 0; kk < KQ; kk += 4) {
    float a0 = 0.f, a1 = 0.f, a2 = 0.f, a3 = 0.f;
    const float4* e0p = ldsE[kk + 0];
    const float4* e1p = ldsE[kk + 1];
    const float4* e2p = ldsE[kk + 2];
    const float4* e3p = ldsE[kk + 3];
#pragma unroll
    for (int dv = 0; dv < 16; ++dv) {
      const float4 e0 = e0p[dv];     // uniform addr -> LDS broadcast
      const float4 e1 = e1p[dv];
      const float4 e2 = e2p[dv];
      const float4 e3 = e3p[dv];
      const float z0 = z[4 * dv + 0], z1 = z[4 * dv + 1];
      const float z2 = z[4 * dv + 2], z3 = z[4 * dv + 3];
      a0 = fmaf(z0, e0.x, a0); a0 = fmaf(z1, e0.y, a0);
      a0 = fmaf(z2, e0.z, a0); a0 = fmaf(z3, e0.w, a0);
      a1 = fmaf(z0, e1.x, a1); a1 = fmaf(z1, e1.y, a1);
      a1 = fmaf(z2, e1.z, a1); a1 = fmaf(z3, e1.w, a1);
      a2 = fmaf(z0, e2.x, a2); a2 = fmaf(z1, e2.y, a2);
      a2 = fmaf(z2, e2.z, a2); a2 = fmaf(z3, e2.w, a2);
      a3 = fmaf(z0, e3.x, a3); a3 = fmaf(z1, e3.y, a3);
      a3 = fmaf(z2, e3.z, a3); a3 = fmaf(z3, e3.w, a3);
    }
    const int kg = kqbase + kk;
    float d;
    // dist = (szz + see_k) - 2*t_k  (exact fp32 order, matches reference)
    d = (szz + ldsS[kk + 0]) - 2.f * a0; if (d < best) { best = d; bidx = kg; }
    d = (szz + ldsS[kk + 1]) - 2.f * a1; if (d < best) { best = d; bidx = kg + 1; }
    d = (szz + ldsS[kk + 2]) - 2.f * a2; if (d < best) { best = d; bidx = kg + 2; }
    d = (szz + ldsS[kk + 3]) - 2.f * a3; if (d < best) { best = d; bidx = kg + 3; }
  }

  float2 p;
  p.x = best;
  p.y = __int_as_float(bidx);
  pairs[(size_t)kq * NTOK + tok] = p;
}

// Combine slices + epilogue. 2048 blocks x 256 thr.
// Thread = (token, d-quarter): wave = 64 consecutive tokens, one d-quarter.
// 8192 waves total (32/CU) -> latency fully hidden by TLP.
__global__ __launch_bounds__(256) void vq_epilogue_kernel(
    const float* __restrict__ z_e, const float* __restrict__ emb,
    const float2* __restrict__ pairs, float* __restrict__ out,
    float* __restrict__ out_idx, int* __restrict__ counts,
    double* __restrict__ sums) {
  __shared__ double sq_s[4];
  __shared__ double md_s[4];

  const int tid = threadIdx.x;
  const int dq  = tid >> 6;                 // 0..3 : d-quarter (16 dims)
  const int tok = blockIdx.x * 64 + (tid & 63);
  const int b   = tok >> 12;
  const int hw  = tok & 4095;

  // combine in ascending slice order, strict < : exact first-occurrence
  float best = 3.4e38f;
  int   bidx = 0;
#pragma unroll
  for (int q = 0; q < NSPLIT; ++q) {
    const float2 p = pairs[(size_t)q * NTOK + tok];
    if (p.x < best) { best = p.x; bidx = __float_as_int(p.y); }
  }

  if (dq == 0) {
    atomicAdd(&counts[bidx], 1);            // direct global hist
    out_idx[tok] = (float)bidx;
  }

  const size_t base = (size_t)b * DDIM * HWSZ + hw + (size_t)(dq * 16) * HWSZ;
  const float* zp = z_e + base;
  float* op = out + base;
  const float4* eq = reinterpret_cast<const float4*>(emb + bidx * DDIM) + dq * 4;

  double sq = 0.0;
#pragma unroll
  for (int d4 = 0; d4 < 4; ++d4) {
    const float4 q = eq[d4];
    const float zq[4] = {q.x, q.y, q.z, q.w};
#pragma unroll
    for (int c = 0; c < 4; ++c) {
      const int d = 4 * d4 + c;
      const float ze  = zp[(size_t)d * HWSZ];
      const float df  = zq[c] - ze;          // fp32 round
      const float val = ze + df;             // z_e + (z_q - z_e), fp32 round
      op[(size_t)d * HWSZ] = val;
      sq = fma((double)df, (double)df, sq);
    }
  }

  double md = (dq == 0) ? (double)best : 0.0;
#pragma unroll
  for (int off = 32; off > 0; off >>= 1) {
    sq += __shfl_down(sq, off);
    md += __shfl_down(md, off);
  }
  const int wave = tid >> 6;
  if ((tid & 63) == 0) { sq_s[wave] = sq; md_s[wave] = md; }
  __syncthreads();
  if (tid == 0) {
    double tsq = sq_s[0] + sq_s[1] + sq_s[2] + sq_s[3];
    double tmd = md_s[0] + md_s[1] + md_s[2] + md_s[3];
    unsafeAtomicAdd(&sums[0], tsq);
    unsafeAtomicAdd(&sums[1], tmd);
  }
}

__global__ void vq_final_kernel(const int* __restrict__ counts,
                                const double* __restrict__ sums,
                                float* __restrict__ scal) {
  __shared__ double ent_s[8];
  __shared__ int    used_s[8];
  const int tid = threadIdx.x;  // 512 threads
  const int c = counts[tid];
  const double p = (double)c / 131072.0;
  double e = (c > 0) ? (-p * log(p)) : 0.0;
  int u = (c > 0) ? 1 : 0;
#pragma unroll
  for (int off = 32; off > 0; off >>= 1) {
    e += __shfl_down(e, off);
    u += __shfl_down(u, off);
  }
  if ((tid & 63) == 0) { ent_s[tid >> 6] = e; used_s[tid >> 6] = u; }
  __syncthreads();
  if (tid == 0) {
    double ent = 0.0; int used = 0;
#pragma unroll
    for (int w = 0; w < 8; ++w) { ent += ent_s[w]; used += used_s[w]; }
    const double mse = sums[0] / 8388608.0;        // mean over B*D*H*W
    scal[0] = (float)(mse * 64.0 * 1.25);          // loss_vq = (1+beta)*mse*D
    scal[1] = (float)exp(ent);                     // perplexity
    scal[2] = (float)used;                         // codes_used
    scal[3] = (float)used / 512.f;                 // usage_ratio
    scal[4] = (float)(sums[1] / 131072.0);         // avg_dist2
  }
}

extern "C" void kernel_launch(void* const* d_in, const int* in_sizes, int n_in,
                              void* d_out, int out_size, void* d_ws,
                              size_t ws_size, hipStream_t stream) {
  const float* z_e = (const float*)d_in[0];
  const float* emb = (const float*)d_in[1];
  float* out = (float*)d_out;

  double* sums   = (double*)d_ws;
  int*    counts = (int*)((char*)d_ws + 16);
  float*  see    = (float*)((char*)d_ws + 2064);
  float2* pairs  = (float2*)((char*)d_ws + 4608);

  hipMemsetAsync(d_ws, 0, 2064, stream);
  vq_see_kernel<<<8, 64, 0, stream>>>(emb, see);
  vq_search_kernel<<<2048, 256, 0, stream>>>(z_e, emb, see, pairs);
  vq_epilogue_kernel<<<2048, 256, 0, stream>>>(z_e, emb, pairs, out,
                                               out + 8388613, counts, sums);
  vq_final_kernel<<<1, 512, 0, stream>>>(counts, sums, out + 8388608);
}